// Round 7
// baseline (623.129 us; speedup 1.0000x reference)
//
#include <hip/hip_runtime.h>
#include <hip/hip_bf16.h>

// SRU cell, fully fused: u = x@W computed on-the-fly inside the scan kernel.
// L=1024, B=32, d=512. Block = one (b, 64-channel group): 6 waves =
//   waves 0-2: MFMA (each owns ONE u-component = 64 cols; breg[16][4] in VGPRs,
//              A-frag reused x4 -> xbuf read volume halved vs R6's 6-wave form)
//   wave 3:    x producer (fp32 global -> bf16 swizzled LDS, double-buffered)
//   wave 4:    c-chain (u0/u1 force-pinned to regs, minimal serial recurrence,
//              cc -> ccbuf)
//   wave 5:    post (2 stages behind: r/tanh/h from ccbuf+u2+x, stores h)
// One raw s_barrier + lgkmcnt(0) per 16-step stage; 66 uniform iterations.
// R6 post-mortem: stage was gated by the LDS pipe (96 b128 xbuf reads/stage/
// block, ~4300cy/CU of LDS traffic vs 5300cy stage). This cuts read volume 2x
// and decouples the scan's serial chain from the h-computation.
// ws: Wt (bf16 [1536][512], 1.5MB) only.

typedef __attribute__((ext_vector_type(8))) __bf16 bf16x8;
typedef __attribute__((ext_vector_type(4))) __bf16 bf16x4;
typedef __attribute__((ext_vector_type(4))) float floatx4;

#define WAITV(N) asm volatile("s_waitcnt vmcnt(" #N ")" ::: "memory")
#define WAITL() asm volatile("s_waitcnt lgkmcnt(0)" ::: "memory")

#define GK 512
#define GN 1536

// ---- weight transpose: W[K][N] fp32 -> Wt[N][K] bf16, LDS-tiled -------------
__global__ __launch_bounds__(256) void cvt_w(const float* __restrict__ w,
                                             __bf16* __restrict__ wt) {
  __shared__ float tile[64][65];
  const int bk = blockIdx.x;  // 8 tiles along K
  const int bn = blockIdx.y;  // 24 tiles along N
  const int t = threadIdx.x;
  const int tr = t >> 6;   // 0..3
  const int tc = t & 63;   // 0..63
#pragma unroll
  for (int i = 0; i < 16; ++i) {
    int kl = i * 4 + tr;
    tile[kl][tc] = w[(size_t)(bk * 64 + kl) * GN + bn * 64 + tc];
  }
  __syncthreads();
#pragma unroll
  for (int i = 0; i < 16; ++i) {
    int nl = i * 4 + tr;
    wt[(size_t)(bn * 64 + nl) * GK + bk * 64 + tc] = (__bf16)tile[tc][nl];
  }
}

// ---- fused GEMM + scan ------------------------------------------------------
// 256 blocks x 384 threads, 2 blocks/CU. XCD-aware mapping: XCD x hosts b in
// {4x..4x+3}; the 8 blocks sharing a batch read x[b] through one L2.
__global__ __launch_bounds__(384, 3) void fused_kernel(
    const float* __restrict__ x, const __bf16* __restrict__ wt,
    const float* __restrict__ wc, const float* __restrict__ bias,
    const float* __restrict__ c0, float* __restrict__ out) {
  // xbuf: 16 t-rows x 512 k bf16, XOR-swizzled (chunk ^= row&7), double-buf
  // ubuf: 16 t-rows x 192 cols fp32, pad 194 (writes 2-way = free), TRIPLE-buf
  //       (post wave lags 2 stages)
  // ccbuf: c values handed chain -> post, double-buf
  __shared__ __attribute__((aligned(16))) __bf16 xbuf[2][16 * 512];
  __shared__ __attribute__((aligned(16))) float ubuf[3][16][194];
  __shared__ __attribute__((aligned(16))) float ccbuf[2][16][64];
  const int g = blockIdx.x;
  const int b = (g & 7) * 4 + ((g >> 3) & 3);
  const int j0 = (g >> 5) * 64;
  const int wave = threadIdx.x >> 6;
  const int lane = threadIdx.x & 63;
  const int quad = lane >> 4, l16 = lane & 15;
  const float L2E = 1.4426950408889634f;

  if (wave < 3) {
    // ---------------- MFMA role: wave w owns component w (64 cols) ----------
    const int nb = wave * 512 + j0;  // global col base in Wt
    const int lnb = wave * 64;       // local col base in ubuf
    bf16x8 breg[16][4];
#pragma unroll
    for (int ki = 0; ki < 16; ++ki)
#pragma unroll
      for (int nt = 0; nt < 4; ++nt)
        breg[ki][nt] = *(const bf16x8*)(wt + (size_t)(nb + nt * 16 + l16) * GK +
                                        ki * 32 + quad * 8);
    __builtin_amdgcn_s_barrier();  // prime (xbuf[0] ready)
    int pu = 0;                    // s % 3
    for (int s = 0; s < 66; ++s) {
      if (s < 64) {
        const __bf16* xb = xbuf[s & 1];
        floatx4 acc[4] = {};
#pragma unroll
        for (int ki = 0; ki < 16; ++ki) {
          bf16x8 af = *(const bf16x8*)(xb + l16 * 512 +
                                       (((4 * ki + quad) ^ (l16 & 7)) * 8));
#pragma unroll
          for (int nt = 0; nt < 4; ++nt)
            acc[nt] = __builtin_amdgcn_mfma_f32_16x16x32_bf16(af, breg[ki][nt],
                                                              acc[nt], 0, 0, 0);
        }
        // D layout: row(t)=quad*4+i, col(n)=l16 (m89-verified)
        float* ub = &ubuf[pu][0][0];
#pragma unroll
        for (int nt = 0; nt < 4; ++nt)
#pragma unroll
          for (int i = 0; i < 4; ++i)
            ub[(quad * 4 + i) * 194 + lnb + nt * 16 + l16] = acc[nt][i];
        pu = (pu == 2) ? 0 : pu + 1;
      }
      WAITL();
      __builtin_amdgcn_s_barrier();
    }
  } else if (wave == 3) {
    // ---------------- x producer role ----------------
    const float* xsrc = x + (size_t)b * 512;
    float4 xr[32];
#define XISSUE(BLK)                                                         \
  _Pragma("unroll") for (int v = 0; v < 32; ++v) {                          \
    int r = v >> 1;                                                         \
    int fq = (v & 1) * 64 + lane;                                           \
    xr[v] = *(const float4*)(xsrc + (size_t)((BLK) * 16 + r) * 16384 + fq * 4); \
  }
#define XWRITE(BUF)                                                         \
  _Pragma("unroll") for (int v = 0; v < 32; ++v) {                          \
    int r = v >> 1;                                                         \
    int fq = (v & 1) * 64 + lane;                                           \
    float4 w4 = xr[v];                                                      \
    bf16x4 o = {(__bf16)w4.x, (__bf16)w4.y, (__bf16)w4.z, (__bf16)w4.w};    \
    *(bf16x4*)((__bf16*)xbuf[BUF] + r * 512 + (((fq >> 1) ^ (r & 7)) * 8) + \
               (fq & 1) * 4) = o;                                           \
  }
    XISSUE(0);
    WAITV(0);
    XWRITE(0);
    XISSUE(1);  // stage-ahead
    WAITL();
    __builtin_amdgcn_s_barrier();  // prime
    for (int s = 0; s < 66; ++s) {
      if (s + 1 < 64) {
        WAITV(0);             // regs for x-tile s+1 landed
        XWRITE((s + 1) & 1);  // gemm reads xbuf[s&1] concurrently
      }
      if (s + 2 < 64) XISSUE(s + 2);
      WAITL();
      __builtin_amdgcn_s_barrier();
    }
#undef XISSUE
#undef XWRITE
  } else if (wave == 4) {
    // ---------------- c-chain role ----------------
    const int ob = b * 512 + j0 + lane;
    const float vf = wc[j0 + lane], bfv = bias[j0 + lane];
    const float wf2 = -vf * L2E;  // sigmoid via exp2
    float c = c0[ob];
    __builtin_amdgcn_s_barrier();  // prime
    int q = 0;                     // (s-1) % 3
    for (int s = 0; s < 66; ++s) {
      if (s >= 1 && s <= 64) {     // process u-stage s-1
        const float* ub = &ubuf[q][0][0];
        float u0a[16], k2a[16];
#pragma unroll
        for (int i = 0; i < 16; ++i) {
          u0a[i] = ub[i * 194 + lane];
          k2a[i] = -(ub[i * 194 + 64 + lane] + bfv) * L2E;
        }
        // force materialization: chain below must be pure-VALU (no sunk loads)
#pragma unroll
        for (int i = 0; i < 16; ++i)
          asm volatile("" : "+v"(u0a[i]), "+v"(k2a[i]));
        __builtin_amdgcn_sched_barrier(0);
        float* cb = &ccbuf[(s - 1) & 1][0][0];
#pragma unroll
        for (int i = 0; i < 16; ++i) {
          float t = __builtin_fmaf(wf2, c, k2a[i]);
          float e;
          asm("v_exp_f32 %0, %1" : "=v"(e) : "v"(t));
          float fr = __builtin_amdgcn_rcpf(1.f + e);
          c = __builtin_fmaf(c - u0a[i], fr, u0a[i]);
          cb[i * 64 + lane] = c;
        }
        q = (q == 2) ? 0 : q + 1;
      }
      WAITL();
      __builtin_amdgcn_s_barrier();
    }
  } else {
    // ---------------- post role (2 stages behind) ----------------
    const int ob = b * 512 + j0 + lane;
    const float vr = wc[512 + j0 + lane], brv = bias[512 + j0 + lane];
    const float wr2 = -vr * L2E;
    float* op = out + ob;
    const float* xs2 = x + ob;
    float xA[16], xB[16];
    int qp = 0;  // d % 3 for d = s-2
    __builtin_amdgcn_s_barrier();  // prime
#define XLOADP(BANK, BLK)                                                   \
  _Pragma("unroll") for (int i = 0; i < 16; ++i) BANK[i] =                  \
      xs2[(size_t)((BLK) * 16 + i) * 16384];
#define PCONS(D, BANK)                                                      \
  {                                                                         \
    const float* ub = &ubuf[qp][0][0];                                      \
    const float* cb = &ccbuf[(D) & 1][0][0];                                \
    _Pragma("unroll") for (int i = 0; i < 16; ++i) {                        \
      float ci = cb[i * 64 + lane];                                         \
      float u2 = ub[i * 194 + 128 + lane];                                  \
      float t2 = __builtin_fmaf(wr2, ci, -(u2 + brv) * L2E);                \
      float e2;                                                             \
      asm("v_exp_f32 %0, %1" : "=v"(e2) : "v"(t2));                         \
      float rg = __builtin_amdgcn_rcpf(1.f + e2);                           \
      float t3 = __builtin_fabsf(ci) * (-2.f * L2E);                        \
      float e3;                                                             \
      asm("v_exp_f32 %0, %1" : "=v"(e3) : "v"(t3));                         \
      float gg = (1.f - e3) * __builtin_amdgcn_rcpf(1.f + e3);              \
      gg = __builtin_copysignf(gg, ci);                                     \
      float xsc = BANK[i] * 1.7320508075688772f;                            \
      float h = __builtin_fmaf(rg, gg - xsc, xsc);                          \
      op[(size_t)((D) * 16 + i) * 16384] = h;                               \
    }                                                                       \
    qp = (qp == 2) ? 0 : qp + 1;                                            \
  }
#define PITER(S, LB, CB)                                                    \
  {                                                                         \
    if ((S) >= 1 && (S) <= 64) XLOADP(LB, (S) - 1);                         \
    if ((S) >= 2) {                                                         \
      WAITV(16); /* retires x-loads(S-2) + stores(S-3); leaves loads(S-1) */\
      PCONS((S) - 2, CB);                                                   \
    }                                                                       \
    __builtin_amdgcn_s_barrier();                                           \
  }
    for (int sp = 0; sp < 66; sp += 2) {
      PITER(sp, xB, xA);      // even s: load->xB (stage sp-1), consume xA
      PITER(sp + 1, xA, xB);  // odd s:  load->xA, consume xB
    }
#undef XLOADP
#undef PCONS
#undef PITER
    // c_last = c after step 1023 = cc of stage 63, step 15 (slot 63&1 = 1)
    out[(size_t)16777216 + ob] = (&ccbuf[1][0][0])[15 * 64 + lane];
  }
}

extern "C" void kernel_launch(void* const* d_in, const int* in_sizes, int n_in,
                              void* d_out, int out_size, void* d_ws, size_t ws_size,
                              hipStream_t stream) {
  const float* x = (const float*)d_in[0];     // (1024,32,512) fp32
  const float* w = (const float*)d_in[1];     // (512,1536)    fp32
  const float* wc = (const float*)d_in[2];    // (1024,)       fp32
  const float* bias = (const float*)d_in[3];  // (1024,)       fp32
  const float* c0 = (const float*)d_in[4];    // (32,512)      fp32
  float* out = (float*)d_out;                 // h (L,B,d) | c_last (B,d)

  char* ws = (char*)d_ws;
  __bf16* wt = (__bf16*)ws;  // 1,572,864 B

  cvt_w<<<dim3(8, 24), 256, 0, stream>>>(w, wt);
  fused_kernel<<<256, 384, 0, stream>>>(x, wt, wc, bias, c0, out);
}

// Round 8
// 287.143 us; speedup vs baseline: 2.1701x; 2.1701x over previous
//
#include <hip/hip_runtime.h>
#include <hip/hip_bf16.h>

// SRU cell, fully fused: u = x@W computed on-the-fly inside the scan kernel.
// L=1024, B=32, d=512. Block = one (b, 64-channel group): 6 waves =
//   waves 0-2: MFMA (each owns ONE u-component = 64 cols; breg[16][4] = 256
//              regs in the unified VGPR/AGPR file, A-frag reused x4)
//   wave 3:    x producer (fp32 global -> bf16 swizzled LDS, double-buffered)
//   wave 4:    c-chain (u0/u1 pinned to regs, minimal serial recurrence -> ccbuf)
//   wave 5:    post (2 stages behind: r/tanh/h from ccbuf+u2+x, stores h)
// One raw s_barrier + lgkmcnt(0) per 16-step stage; 66 uniform iterations.
// R7 post-mortem: __launch_bounds__(384,3) capped VGPRs at ~170 < breg's 256
// -> W spilled, refetched from global EVERY stage (FETCH 39->380MB, MfmaUtil
// 3.8%). This round: identical kernel, launch_bounds(384) -- allocator free.
// ws: Wt (bf16 [1536][512], 1.5MB) only.

typedef __attribute__((ext_vector_type(8))) __bf16 bf16x8;
typedef __attribute__((ext_vector_type(4))) __bf16 bf16x4;
typedef __attribute__((ext_vector_type(4))) float floatx4;

#define WAITV(N) asm volatile("s_waitcnt vmcnt(" #N ")" ::: "memory")
#define WAITL() asm volatile("s_waitcnt lgkmcnt(0)" ::: "memory")

#define GK 512
#define GN 1536

// ---- weight transpose: W[K][N] fp32 -> Wt[N][K] bf16, LDS-tiled -------------
__global__ __launch_bounds__(256) void cvt_w(const float* __restrict__ w,
                                             __bf16* __restrict__ wt) {
  __shared__ float tile[64][65];
  const int bk = blockIdx.x;  // 8 tiles along K
  const int bn = blockIdx.y;  // 24 tiles along N
  const int t = threadIdx.x;
  const int tr = t >> 6;   // 0..3
  const int tc = t & 63;   // 0..63
#pragma unroll
  for (int i = 0; i < 16; ++i) {
    int kl = i * 4 + tr;
    tile[kl][tc] = w[(size_t)(bk * 64 + kl) * GN + bn * 64 + tc];
  }
  __syncthreads();
#pragma unroll
  for (int i = 0; i < 16; ++i) {
    int nl = i * 4 + tr;
    wt[(size_t)(bn * 64 + nl) * GK + bk * 64 + tc] = (__bf16)tile[tc][nl];
  }
}

// ---- fused GEMM + scan ------------------------------------------------------
// 256 blocks x 384 threads, 2 blocks/CU (LDS-bound: 78KB). XCD-aware mapping:
// XCD x hosts b in {4x..4x+3}; 8 blocks sharing a batch read x[b] via one L2.
__global__ __launch_bounds__(384) void fused_kernel(
    const float* __restrict__ x, const __bf16* __restrict__ wt,
    const float* __restrict__ wc, const float* __restrict__ bias,
    const float* __restrict__ c0, float* __restrict__ out) {
  // xbuf: 16 t-rows x 512 k bf16, XOR-swizzled (chunk ^= row&7), double-buf
  // ubuf: 16 t-rows x 192 cols fp32, pad 194 (writes 2-way = free), TRIPLE-buf
  //       (post wave lags 2 stages)
  // ccbuf: c values handed chain -> post, double-buf
  __shared__ __attribute__((aligned(16))) __bf16 xbuf[2][16 * 512];
  __shared__ __attribute__((aligned(16))) float ubuf[3][16][194];
  __shared__ __attribute__((aligned(16))) float ccbuf[2][16][64];
  const int g = blockIdx.x;
  const int b = (g & 7) * 4 + ((g >> 3) & 3);
  const int j0 = (g >> 5) * 64;
  const int wave = threadIdx.x >> 6;
  const int lane = threadIdx.x & 63;
  const int quad = lane >> 4, l16 = lane & 15;
  const float L2E = 1.4426950408889634f;

  if (wave < 3) {
    // ---------------- MFMA role: wave w owns component w (64 cols) ----------
    const int nb = wave * 512 + j0;  // global col base in Wt
    const int lnb = wave * 64;       // local col base in ubuf
    bf16x8 breg[16][4];
#pragma unroll
    for (int ki = 0; ki < 16; ++ki)
#pragma unroll
      for (int nt = 0; nt < 4; ++nt)
        breg[ki][nt] = *(const bf16x8*)(wt + (size_t)(nb + nt * 16 + l16) * GK +
                                        ki * 32 + quad * 8);
    __builtin_amdgcn_s_barrier();  // prime (xbuf[0] ready)
    int pu = 0;                    // s % 3
    for (int s = 0; s < 66; ++s) {
      if (s < 64) {
        const __bf16* xb = xbuf[s & 1];
        floatx4 acc[4] = {};
#pragma unroll
        for (int ki = 0; ki < 16; ++ki) {
          bf16x8 af = *(const bf16x8*)(xb + l16 * 512 +
                                       (((4 * ki + quad) ^ (l16 & 7)) * 8));
#pragma unroll
          for (int nt = 0; nt < 4; ++nt)
            acc[nt] = __builtin_amdgcn_mfma_f32_16x16x32_bf16(af, breg[ki][nt],
                                                              acc[nt], 0, 0, 0);
        }
        // D layout: row(t)=quad*4+i, col(n)=l16 (m89-verified)
        float* ub = &ubuf[pu][0][0];
#pragma unroll
        for (int nt = 0; nt < 4; ++nt)
#pragma unroll
          for (int i = 0; i < 4; ++i)
            ub[(quad * 4 + i) * 194 + lnb + nt * 16 + l16] = acc[nt][i];
        pu = (pu == 2) ? 0 : pu + 1;
      }
      WAITL();
      __builtin_amdgcn_s_barrier();
    }
  } else if (wave == 3) {
    // ---------------- x producer role ----------------
    const float* xsrc = x + (size_t)b * 512;
    float4 xr[32];
#define XISSUE(BLK)                                                         \
  _Pragma("unroll") for (int v = 0; v < 32; ++v) {                          \
    int r = v >> 1;                                                         \
    int fq = (v & 1) * 64 + lane;                                           \
    xr[v] = *(const float4*)(xsrc + (size_t)((BLK) * 16 + r) * 16384 + fq * 4); \
  }
#define XWRITE(BUF)                                                         \
  _Pragma("unroll") for (int v = 0; v < 32; ++v) {                          \
    int r = v >> 1;                                                         \
    int fq = (v & 1) * 64 + lane;                                           \
    float4 w4 = xr[v];                                                      \
    bf16x4 o = {(__bf16)w4.x, (__bf16)w4.y, (__bf16)w4.z, (__bf16)w4.w};    \
    *(bf16x4*)((__bf16*)xbuf[BUF] + r * 512 + (((fq >> 1) ^ (r & 7)) * 8) + \
               (fq & 1) * 4) = o;                                           \
  }
    XISSUE(0);
    WAITV(0);
    XWRITE(0);
    XISSUE(1);  // stage-ahead
    WAITL();
    __builtin_amdgcn_s_barrier();  // prime
    for (int s = 0; s < 66; ++s) {
      if (s + 1 < 64) {
        WAITV(0);             // regs for x-tile s+1 landed
        XWRITE((s + 1) & 1);  // gemm reads xbuf[s&1] concurrently
      }
      if (s + 2 < 64) XISSUE(s + 2);
      WAITL();
      __builtin_amdgcn_s_barrier();
    }
#undef XISSUE
#undef XWRITE
  } else if (wave == 4) {
    // ---------------- c-chain role ----------------
    const int ob = b * 512 + j0 + lane;
    const float vf = wc[j0 + lane], bfv = bias[j0 + lane];
    const float wf2 = -vf * L2E;  // sigmoid via exp2
    float c = c0[ob];
    __builtin_amdgcn_s_barrier();  // prime
    int q = 0;                     // (s-1) % 3
    for (int s = 0; s < 66; ++s) {
      if (s >= 1 && s <= 64) {     // process u-stage s-1
        const float* ub = &ubuf[q][0][0];
        float u0a[16], k2a[16];
#pragma unroll
        for (int i = 0; i < 16; ++i) {
          u0a[i] = ub[i * 194 + lane];
          k2a[i] = -(ub[i * 194 + 64 + lane] + bfv) * L2E;
        }
        // force materialization: chain below must be pure-VALU (no sunk loads)
#pragma unroll
        for (int i = 0; i < 16; ++i)
          asm volatile("" : "+v"(u0a[i]), "+v"(k2a[i]));
        __builtin_amdgcn_sched_barrier(0);
        float* cb = &ccbuf[(s - 1) & 1][0][0];
#pragma unroll
        for (int i = 0; i < 16; ++i) {
          float t = __builtin_fmaf(wf2, c, k2a[i]);
          float e;
          asm("v_exp_f32 %0, %1" : "=v"(e) : "v"(t));
          float fr = __builtin_amdgcn_rcpf(1.f + e);
          c = __builtin_fmaf(c - u0a[i], fr, u0a[i]);
          cb[i * 64 + lane] = c;
        }
        q = (q == 2) ? 0 : q + 1;
      }
      WAITL();
      __builtin_amdgcn_s_barrier();
    }
  } else {
    // ---------------- post role (2 stages behind) ----------------
    const int ob = b * 512 + j0 + lane;
    const float vr = wc[512 + j0 + lane], brv = bias[512 + j0 + lane];
    const float wr2 = -vr * L2E;
    float* op = out + ob;
    const float* xs2 = x + ob;
    float xA[16], xB[16];
    int qp = 0;  // d % 3 for d = s-2
    __builtin_amdgcn_s_barrier();  // prime
#define XLOADP(BANK, BLK)                                                   \
  _Pragma("unroll") for (int i = 0; i < 16; ++i) BANK[i] =                  \
      xs2[(size_t)((BLK) * 16 + i) * 16384];
#define PCONS(D, BANK)                                                      \
  {                                                                         \
    const float* ub = &ubuf[qp][0][0];                                      \
    const float* cb = &ccbuf[(D) & 1][0][0];                                \
    _Pragma("unroll") for (int i = 0; i < 16; ++i) {                        \
      float ci = cb[i * 64 + lane];                                         \
      float u2 = ub[i * 194 + 128 + lane];                                  \
      float t2 = __builtin_fmaf(wr2, ci, -(u2 + brv) * L2E);                \
      float e2;                                                             \
      asm("v_exp_f32 %0, %1" : "=v"(e2) : "v"(t2));                         \
      float rg = __builtin_amdgcn_rcpf(1.f + e2);                           \
      float t3 = __builtin_fabsf(ci) * (-2.f * L2E);                        \
      float e3;                                                             \
      asm("v_exp_f32 %0, %1" : "=v"(e3) : "v"(t3));                         \
      float gg = (1.f - e3) * __builtin_amdgcn_rcpf(1.f + e3);              \
      gg = __builtin_copysignf(gg, ci);                                     \
      float xsc = BANK[i] * 1.7320508075688772f;                            \
      float h = __builtin_fmaf(rg, gg - xsc, xsc);                          \
      op[(size_t)((D) * 16 + i) * 16384] = h;                               \
    }                                                                       \
    qp = (qp == 2) ? 0 : qp + 1;                                            \
  }
#define PITER(S, LB, CB)                                                    \
  {                                                                         \
    if ((S) >= 1 && (S) <= 64) XLOADP(LB, (S) - 1);                         \
    if ((S) >= 2) {                                                         \
      WAITV(16); /* retires x-loads(S-2) + stores(S-3); leaves loads(S-1) */\
      PCONS((S) - 2, CB);                                                   \
    }                                                                       \
    __builtin_amdgcn_s_barrier();                                           \
  }
    for (int sp = 0; sp < 66; sp += 2) {
      PITER(sp, xB, xA);      // even s: load->xB (stage sp-1), consume xA
      PITER(sp + 1, xA, xB);  // odd s:  load->xA, consume xB
    }
#undef XLOADP
#undef PCONS
#undef PITER
    // c_last = c after step 1023 = cc of stage 63, step 15 (slot 63&1 = 1)
    out[(size_t)16777216 + ob] = (&ccbuf[1][0][0])[15 * 64 + lane];
  }
}

extern "C" void kernel_launch(void* const* d_in, const int* in_sizes, int n_in,
                              void* d_out, int out_size, void* d_ws, size_t ws_size,
                              hipStream_t stream) {
  const float* x = (const float*)d_in[0];     // (1024,32,512) fp32
  const float* w = (const float*)d_in[1];     // (512,1536)    fp32
  const float* wc = (const float*)d_in[2];    // (1024,)       fp32
  const float* bias = (const float*)d_in[3];  // (1024,)       fp32
  const float* c0 = (const float*)d_in[4];    // (32,512)      fp32
  float* out = (float*)d_out;                 // h (L,B,d) | c_last (B,d)

  char* ws = (char*)d_ws;
  __bf16* wt = (__bf16*)ws;  // 1,572,864 B

  cvt_w<<<dim3(8, 24), 256, 0, stream>>>(w, wt);
  fused_kernel<<<256, 384, 0, stream>>>(x, wt, wc, bias, c0, out);
}

// Round 9
// 222.920 us; speedup vs baseline: 2.7953x; 1.2881x over previous
//
#include <hip/hip_runtime.h>
#include <hip/hip_bf16.h>

// SRU cell, fully fused: u = x@W computed on-the-fly inside the scan kernel.
// L=1024, B=32, d=512. 256 blocks (1 per CU) x 512 thr = 8 waves:
//   waves 0-5: MFMA (R6-proven: each owns 32 cols, breg[16][2], 2 chains/read)
//   wave 6:    c-chain ONLY (minimal serial recurrence, lag 1, c -> ccbuf)
//   wave 7:    producer (x fp32->bf16 swizzled LDS, 1 ahead) + post (lag 2:
//              r/tanh/h from ccbuf+u2+xbuf-bf16, h stores)
// R8 post-mortem: grid=256 => 1 block/CU always; stage time is the barrier-
// coupled max over role serial times. R6's fat single scan wave (~2400cy) and
// R8's exposed-LDS-latency fat MFMA waves were the gates. This round keeps
// R6's thin MFMA/producer codegen and splits the scan's serial chain (wave 6)
// from its ILP-rich post work (folded into wave 7).
// Buffers: xbuf[4] (producer writes s+1, gemm reads s, post reads s-2),
// ubuf[3] (gemm s, chain s-1, post s-2), ccbuf[2] (chain s-1, post s-2).
// ws: Wt (bf16 [1536][512], 1.5MB) only.

typedef __attribute__((ext_vector_type(8))) __bf16 bf16x8;
typedef __attribute__((ext_vector_type(4))) __bf16 bf16x4;
typedef __attribute__((ext_vector_type(4))) float floatx4;

#define WAITV(N) asm volatile("s_waitcnt vmcnt(" #N ")" ::: "memory")
#define WAITL() asm volatile("s_waitcnt lgkmcnt(0)" ::: "memory")

#define GK 512
#define GN 1536

// ---- weight transpose: W[K][N] fp32 -> Wt[N][K] bf16, LDS-tiled -------------
__global__ __launch_bounds__(256) void cvt_w(const float* __restrict__ w,
                                             __bf16* __restrict__ wt) {
  __shared__ float tile[64][65];
  const int bk = blockIdx.x;  // 8 tiles along K
  const int bn = blockIdx.y;  // 24 tiles along N
  const int t = threadIdx.x;
  const int tr = t >> 6;   // 0..3
  const int tc = t & 63;   // 0..63
#pragma unroll
  for (int i = 0; i < 16; ++i) {
    int kl = i * 4 + tr;
    tile[kl][tc] = w[(size_t)(bk * 64 + kl) * GN + bn * 64 + tc];
  }
  __syncthreads();
#pragma unroll
  for (int i = 0; i < 16; ++i) {
    int nl = i * 4 + tr;
    wt[(size_t)(bn * 64 + nl) * GK + bk * 64 + tc] = (__bf16)tile[tc][nl];
  }
}

// ---- fused GEMM + scan ------------------------------------------------------
// XCD-aware mapping: XCD x hosts b in {4x..4x+3}; the 8 blocks sharing a batch
// read x[b] through one L2.
__global__ __launch_bounds__(512, 1) void fused_kernel(
    const float* __restrict__ x, const __bf16* __restrict__ wt,
    const float* __restrict__ wc, const float* __restrict__ bias,
    const float* __restrict__ c0, float* __restrict__ out) {
  __shared__ __attribute__((aligned(16))) __bf16 xbuf[4][16 * 512];  // 64 KB
  __shared__ __attribute__((aligned(16))) float ubuf[3][16][194];    // 37 KB
  __shared__ __attribute__((aligned(16))) float ccbuf[2][16][64];    // 8 KB
  const int g = blockIdx.x;
  const int b = (g & 7) * 4 + ((g >> 3) & 3);
  const int j0 = (g >> 5) * 64;
  const int wave = threadIdx.x >> 6;
  const int lane = threadIdx.x & 63;
  const int quad = lane >> 4, l16 = lane & 15;
  const float L2E = 1.4426950408889634f;

  if (wave < 6) {
    // ---------------- MFMA role (R6-proven shape) ----------------
    const int comp = wave >> 1, hn = wave & 1;  // component 0..2, half 0..1
    const int lnb = comp * 64 + hn * 32;        // local col base in ubuf
    const int nb = comp * 512 + j0 + hn * 32;   // global col base in Wt
    bf16x8 breg[16][2];
#pragma unroll
    for (int ki = 0; ki < 16; ++ki)
#pragma unroll
      for (int nt = 0; nt < 2; ++nt)
        breg[ki][nt] = *(const bf16x8*)(wt + (size_t)(nb + nt * 16 + l16) * GK +
                                        ki * 32 + quad * 8);
    __builtin_amdgcn_s_barrier();  // prime (xbuf[0] ready)
    int pu = 0;                    // s % 3
    for (int s = 0; s < 66; ++s) {
      if (s < 64) {
        const __bf16* xb = xbuf[s & 3];
        floatx4 acc0 = {}, acc1 = {};
#pragma unroll
        for (int ki = 0; ki < 16; ++ki) {
          bf16x8 af = *(const bf16x8*)(xb + l16 * 512 +
                                       (((4 * ki + quad) ^ (l16 & 7)) * 8));
          acc0 = __builtin_amdgcn_mfma_f32_16x16x32_bf16(af, breg[ki][0], acc0, 0, 0, 0);
          acc1 = __builtin_amdgcn_mfma_f32_16x16x32_bf16(af, breg[ki][1], acc1, 0, 0, 0);
        }
        // D layout: row(t)=quad*4+i, col(n)=l16 (m89-verified)
        float* ub = &ubuf[pu][0][0];
#pragma unroll
        for (int i = 0; i < 4; ++i) {
          ub[(quad * 4 + i) * 194 + lnb + l16] = acc0[i];
          ub[(quad * 4 + i) * 194 + lnb + 16 + l16] = acc1[i];
        }
        pu = (pu == 2) ? 0 : pu + 1;
      }
      WAITL();
      __builtin_amdgcn_s_barrier();
    }
  } else if (wave == 6) {
    // ---------------- c-chain role (lag 1) ----------------
    const int ob = b * 512 + j0 + lane;
    const float vf = wc[j0 + lane], bfv = bias[j0 + lane];
    const float wf2 = -vf * L2E;  // sigmoid via exp2
    float c = c0[ob];
    __builtin_amdgcn_s_barrier();  // prime
    int q = 0;                     // (s-1) % 3
    for (int s = 0; s < 66; ++s) {
      if (s >= 1 && s <= 64) {     // process u-stage s-1
        const float* ub = &ubuf[q][0][0];
        float u0a[16], k2a[16];
#pragma unroll
        for (int i = 0; i < 16; ++i) {
          u0a[i] = ub[i * 194 + lane];
          k2a[i] = -(ub[i * 194 + 64 + lane] + bfv) * L2E;
        }
        // pin: chain below must be pure-VALU (no sunk LDS loads)
#pragma unroll
        for (int i = 0; i < 16; ++i)
          asm volatile("" : "+v"(u0a[i]), "+v"(k2a[i]));
        __builtin_amdgcn_sched_barrier(0);
        float* cb = &ccbuf[(s - 1) & 1][0][0];
#pragma unroll
        for (int i = 0; i < 16; ++i) {
          float t = __builtin_fmaf(wf2, c, k2a[i]);
          float e;
          asm("v_exp_f32 %0, %1" : "=v"(e) : "v"(t));
          float fr = __builtin_amdgcn_rcpf(1.f + e);
          c = __builtin_fmaf(c - u0a[i], fr, u0a[i]);
          cb[i * 64 + lane] = c;
        }
        q = (q == 2) ? 0 : q + 1;
      }
      WAITL();
      __builtin_amdgcn_s_barrier();
    }
  } else {
    // ---------------- producer + post role ----------------
    const int ob = b * 512 + j0 + lane;
    const int cidx = j0 + lane;  // this lane's channel as a K-column of xbuf
    const float vr = wc[512 + j0 + lane], brv = bias[512 + j0 + lane];
    const float wr2 = -vr * L2E;
    float* op = out + ob;
    const float* xsrc = x + (size_t)b * 512;
    float4 xr[32];
#define XISSUE(BLK)                                                         \
  _Pragma("unroll") for (int v = 0; v < 32; ++v) {                          \
    int r = v >> 1;                                                         \
    int fq = (v & 1) * 64 + lane;                                           \
    xr[v] = *(const float4*)(xsrc + (size_t)((BLK) * 16 + r) * 16384 + fq * 4); \
  }
#define XWRITE(SLOT)                                                        \
  _Pragma("unroll") for (int v = 0; v < 32; ++v) {                          \
    int r = v >> 1;                                                         \
    int fq = (v & 1) * 64 + lane;                                           \
    float4 w4 = xr[v];                                                      \
    bf16x4 o = {(__bf16)w4.x, (__bf16)w4.y, (__bf16)w4.z, (__bf16)w4.w};    \
    *(bf16x4*)((__bf16*)xbuf[SLOT] + r * 512 + (((fq >> 1) ^ (r & 7)) * 8) + \
               (fq & 1) * 4) = o;                                           \
  }
#define PPOST(D, QP)                                                        \
  {                                                                         \
    const float* ub = &ubuf[QP][0][0];                                      \
    const float* cb = &ccbuf[(D) & 1][0][0];                                \
    const __bf16* xbp = xbuf[(D) & 3];                                      \
    _Pragma("unroll") for (int i = 0; i < 16; ++i) {                        \
      float ci = cb[i * 64 + lane];                                         \
      float u2 = ub[i * 194 + 128 + lane];                                  \
      float xv = (float)xbp[i * 512 + (((cidx >> 3) ^ (i & 7)) * 8) +       \
                            (cidx & 7)];                                    \
      float t2 = __builtin_fmaf(wr2, ci, -(u2 + brv) * L2E);                \
      float e2;                                                             \
      asm("v_exp_f32 %0, %1" : "=v"(e2) : "v"(t2));                         \
      float rg = __builtin_amdgcn_rcpf(1.f + e2);                           \
      float t3 = __builtin_fabsf(ci) * (-2.f * L2E);                        \
      float e3;                                                             \
      asm("v_exp_f32 %0, %1" : "=v"(e3) : "v"(t3));                         \
      float gg = (1.f - e3) * __builtin_amdgcn_rcpf(1.f + e3);              \
      gg = __builtin_copysignf(gg, ci);                                     \
      float xsc = xv * 1.7320508075688772f;                                 \
      float h = __builtin_fmaf(rg, gg - xsc, xsc);                          \
      op[(size_t)((D) * 16 + i) * 16384] = h;                               \
    }                                                                       \
  }
    // prologue: stage 0 into slot 0, issue stage 1
    XISSUE(0);
    WAITV(0);
    XWRITE(0);
    XISSUE(1);
    WAITL();
    __builtin_amdgcn_s_barrier();  // prime
    int qp = 0;  // (s-2) % 3
    for (int s = 0; s < 66; ++s) {
      if (s + 1 < 64) {
        WAITV(0);              // regs for x-tile s+1 landed (and old stores drained)
        XWRITE((s + 1) & 3);   // gemm reads xbuf[s&3] concurrently (distinct slot)
      }
      if (s + 2 < 64) XISSUE(s + 2);
      if (s >= 2) {            // post for stage s-2 (ubuf/ccbuf barrier-released)
        PPOST(s - 2, qp);
        qp = (qp == 2) ? 0 : qp + 1;
      }
      WAITL();
      __builtin_amdgcn_s_barrier();
    }
#undef XISSUE
#undef XWRITE
#undef PPOST
    // c_last = chain's c after stage 63, step 15 (slot 63&1 = 1)
    out[(size_t)16777216 + ob] = (&ccbuf[1][0][0])[15 * 64 + lane];
  }
}

extern "C" void kernel_launch(void* const* d_in, const int* in_sizes, int n_in,
                              void* d_out, int out_size, void* d_ws, size_t ws_size,
                              hipStream_t stream) {
  const float* x = (const float*)d_in[0];     // (1024,32,512) fp32
  const float* w = (const float*)d_in[1];     // (512,1536)    fp32
  const float* wc = (const float*)d_in[2];    // (1024,)       fp32
  const float* bias = (const float*)d_in[3];  // (1024,)       fp32
  const float* c0 = (const float*)d_in[4];    // (32,512)      fp32
  float* out = (float*)d_out;                 // h (L,B,d) | c_last (B,d)

  char* ws = (char*)d_ws;
  __bf16* wt = (__bf16*)ws;  // 1,572,864 B

  cvt_w<<<dim3(8, 24), 256, 0, stream>>>(w, wt);
  fused_kernel<<<256, 512, 0, stream>>>(x, wt, wc, bias, c0, out);
}